// Round 1
// baseline (1079.102 us; speedup 1.0000x reference)
//
#include <hip/hip_runtime.h>

#define Nn 100000
#define Tt 16
#define Dd 8
#define Hh 40
#define HP1 41
#define XE 50      // Xe = [h0..h39, 1, x0..x7, y]
#define NPAIR 1275 // 50*51/2 symmetric pairs
#define NPADDED 1280
#define NB 64
#define NTILES ((Nn + NB - 1) / NB)
#define GRID1 512

// output offsets (flat, return order)
#define OFF_BG1   0
#define OFF_BG2   16
#define OFF_MU    32
#define OFF_KAPPA 160
#define OFF_NU    176
#define OFF_PSI   192
#define OFF_WM    1216
#define OFF_WS    1872
#define OFF_ZA    28768
#define OFF_ZB    28784
#define OFF_EA    28800
#define OFF_EB    28816

__device__ __forceinline__ int pidx(int i, int j) {
  if (i > j) { int tmp = i; i = j; j = tmp; }
  return (i * (2 * XE - i + 1)) / 2 + (j - i);  // = 50i - i(i-1)/2 + (j-i)
}

__global__ void zero_ws_kernel(float* ws, int n) {
  int i = blockIdx.x * blockDim.x + threadIdx.x;
  if (i < n) ws[i] = 0.f;
}

// ---------------- Kernel 1: weighted Gram reduction ----------------
__global__ __launch_bounds__(256, 2)
void gram_reduce(const float* __restrict__ Phi, const float* __restrict__ Xd,
                 const float* __restrict__ Yd, const float* __restrict__ Welm,
                 const float* __restrict__ belm, float* __restrict__ acc_ws)
{
  __shared__ float sW[Dd * Hh];
  __shared__ float sb[Hh];
  __shared__ float Xs[NB][XE];
  __shared__ float Ps[NB][Tt];

  int tid = threadIdx.x;
  for (int i = tid; i < Dd * Hh; i += 256) sW[i] = Welm[i];
  if (tid < Hh) sb[tid] = belm[tid];

  // pair ownership: up to 5 pairs per thread
  int pi_r[5], pj_r[5];
  bool pv_r[5];
#pragma unroll
  for (int k = 0; k < 5; ++k) {
    int p = tid + k * 256;
    if (p < NPAIR) {
      int i = 0, s = 0;
      while (s + (XE - i) <= p) { s += XE - i; ++i; }
      pi_r[k] = i; pj_r[k] = i + (p - s); pv_r[k] = true;
    } else { pi_r[k] = 0; pj_r[k] = 0; pv_r[k] = false; }
  }

  float acc[5][Tt];
#pragma unroll
  for (int k = 0; k < 5; ++k)
#pragma unroll
    for (int t = 0; t < Tt; ++t) acc[k][t] = 0.f;

  for (int tile = blockIdx.x; tile < NTILES; tile += gridDim.x) {
    int n0 = tile * NB;
    __syncthreads();  // protect Xs/Ps from prior iteration readers
    // stage phi (coalesced: Phi is row-major N x 16)
    for (int idx = tid; idx < NB * Tt; idx += 256) {
      int n = idx / Tt, t = idx % Tt;
      int gn = n0 + n;
      Ps[n][t] = (gn < Nn) ? Phi[gn * Tt + t] : 0.f;
    }
    // stage x
    for (int idx = tid; idx < NB * Dd; idx += 256) {
      int n = idx / Dd, d = idx % Dd;
      int gn = n0 + n;
      Xs[n][41 + d] = (gn < Nn) ? Xd[gn * Dd + d] : 0.f;
    }
    // stage y + constant column
    for (int n = tid; n < NB; n += 256) {
      int gn = n0 + n;
      Xs[n][49] = (gn < Nn) ? Yd[gn] : 0.f;
      Xs[n][40] = 1.f;
    }
    __syncthreads();
    // ELM hidden layer: h = sigmoid(x W + b)
    for (int idx = tid; idx < NB * Hh; idx += 256) {
      int n = idx / Hh, h = idx % Hh;
      float z = sb[h];
#pragma unroll
      for (int d = 0; d < Dd; ++d) z += Xs[n][41 + d] * sW[d * Hh + h];
      Xs[n][h] = 1.f / (1.f + __expf(-z));
    }
    __syncthreads();
    // accumulate: acc[p][t] += phi[n][t] * Xe[n][i] * Xe[n][j]
    for (int n = 0; n < NB; ++n) {
      float ph[Tt];
#pragma unroll
      for (int t = 0; t < Tt; ++t) ph[t] = Ps[n][t];  // LDS broadcast
#pragma unroll
      for (int k = 0; k < 5; ++k) {
        float prod = Xs[n][pi_r[k]] * Xs[n][pj_r[k]];
#pragma unroll
        for (int t = 0; t < Tt; ++t) acc[k][t] = fmaf(prod, ph[t], acc[k][t]);
      }
    }
  }
  // flush partials
#pragma unroll
  for (int k = 0; k < 5; ++k) {
    if (pv_r[k]) {
      int p = tid + k * 256;
      for (int t = 0; t < Tt; ++t) atomicAdd(&acc_ws[p * Tt + t], acc[k][t]);
    }
  }
}

// ---------------- Kernel 2: per-t inversion + all small outputs ----------------
__global__ __launch_bounds__(256)
void finalize_kernel(const float* __restrict__ acc, const float* __restrict__ epsA,
                     const float* __restrict__ epsB, const float* __restrict__ zetA,
                     const float* __restrict__ zetB, float* __restrict__ out)
{
  int t = blockIdx.x;
  int tid = threadIdx.x;
  __shared__ float G[HP1][2 * HP1 + 2];   // augmented [M | I] -> [junk | WS]
  __shared__ float As[HP1][HP1 + 1];
  __shared__ float bs[HP1];
  __shared__ float colk[HP1];
  __shared__ float red[256];
  __shared__ float wmv[HP1];
  __shared__ float mus[Dd];
  __shared__ float pivinv_s;

  float epsExp = epsA[t] / epsB[t];
  float zetaExp = zetA[t] / zetB[t];

  for (int idx = tid; idx < HP1 * HP1; idx += 256) {
    int i = idx / HP1, j = idx % HP1;
    float a = acc[pidx(i, j) * Tt + t];
    As[i][j] = a;
    G[i][j] = epsExp * a + (i == j ? zetaExp : 0.f);
    G[i][HP1 + j] = (i == j) ? 1.f : 0.f;
  }
  if (tid < HP1) bs[tid] = acc[pidx(tid, 49) * Tt + t];
  __syncthreads();

  // Gauss-Jordan (SPD, no pivoting)
  for (int k = 0; k < HP1; ++k) {
    if (tid == 0) pivinv_s = 1.f / G[k][k];
    __syncthreads();
    float pivinv = pivinv_s;
    for (int j = tid; j < 2 * HP1; j += 256) G[k][j] *= pivinv;
    if (tid < HP1) colk[tid] = (tid == k) ? 0.f : G[tid][k];
    __syncthreads();
    for (int idx = tid; idx < HP1 * 2 * HP1; idx += 256) {
      int i = idx / (2 * HP1), j = idx % (2 * HP1);
      if (i != k) G[i][j] -= colk[i] * G[k][j];
    }
    __syncthreads();
  }

  // write WS
  for (int idx = tid; idx < HP1 * HP1; idx += 256) {
    int i = idx / HP1, j = idx % HP1;
    out[OFF_WS + (t * HP1 + i) * HP1 + j] = G[i][HP1 + j];
  }
  // WMv = zetaExp * WS @ b
  if (tid < HP1) {
    float s = 0.f;
    for (int j = 0; j < HP1; ++j) s += G[tid][HP1 + j] * bs[j];
    float w = zetaExp * s;
    wmv[tid] = w;
    out[OFF_WM + t * HP1 + tid] = w;
  }
  __syncthreads();
  // t2 = sum_ij A_ij * WS_ij  (both symmetric)
  float lt2 = 0.f;
  for (int idx = tid; idx < HP1 * HP1; idx += 256) {
    int i = idx / HP1, j = idx % HP1;
    lt2 += As[i][j] * G[i][HP1 + j];
  }
  red[tid] = lt2; __syncthreads();
  for (int s = 128; s > 0; s >>= 1) {
    if (tid < s) red[tid] += red[tid + s];
    __syncthreads();
  }
  float t2v = red[0];

  float sp = acc[pidx(40, 40) * Tt + t];  // sumPhi[t]
  float kap = 1000.f + sp;

  if (tid == 0) {
    float trWS = 0.f, wn = 0.f;
    for (int i = 0; i < HP1; ++i) { trWS += G[i][HP1 + i]; wn += wmv[i] * wmv[i]; }
    out[OFF_BG1 + t] = 1.f + sp;
    float rest = 0.f;
    for (int u = t + 1; u < Tt; ++u) rest += acc[pidx(40, 40) * Tt + u];
    out[OFF_BG2 + t] = 1.f + rest;            // ALPHA_DP = 1
    out[OFF_KAPPA + t] = kap;
    out[OFF_NU + t] = sp + 100.f;             // sumPhi + NU0
    out[OFF_ZA + t] = zetA[t] + 0.5f * (float)HP1;
    out[OFF_ZB + t] = zetB[t] + 0.5f * (wn + trWS);
    out[OFF_EA + t] = epsA[t] + 0.5f * sp;
    out[OFF_EB + t] = epsB[t] + 0.5f * t2v;   // kernel 3 atomically adds 0.5*t1
  }
  // mu
  if (tid < Dd) {
    float m = acc[pidx(40, 41 + tid) * Tt + t] / kap;
    mus[tid] = m;
    out[OFF_MU + tid * Tt + t] = m;
  }
  __syncthreads();
  // psi = 500*I + S - kappa * mu mu^T
  if (tid < Dd * Dd) {
    int i = tid / Dd, j = tid % Dd;
    float S = acc[pidx(41 + i, 41 + j) * Tt + t];
    float v = (i == j ? 500.f : 0.f) + S - kap * mus[i] * mus[j];
    out[OFF_PSI + (i * Dd + j) * Tt + t] = v;
  }
}

// ---------------- Kernel 3: t1 = sum_n phi * err^2 ----------------
__global__ __launch_bounds__(256)
void resid_kernel(const float* __restrict__ Phi, const float* __restrict__ Xd,
                  const float* __restrict__ Yd, const float* __restrict__ Welm,
                  const float* __restrict__ belm, float* __restrict__ out)
{
  __shared__ float sW[Dd * Hh];
  __shared__ float sb[Hh];
  __shared__ float sWM[Tt][HP1];
  __shared__ float red[256];
  int tid = threadIdx.x;
  for (int i = tid; i < Dd * Hh; i += 256) sW[i] = Welm[i];
  if (tid < Hh) sb[tid] = belm[tid];
  for (int i = tid; i < Tt * HP1; i += 256) sWM[i / HP1][i % HP1] = out[OFF_WM + i];
  __syncthreads();

  float acc[Tt];
#pragma unroll
  for (int t = 0; t < Tt; ++t) acc[t] = 0.f;

  int stride = gridDim.x * blockDim.x;
  for (int n = blockIdx.x * blockDim.x + tid; n < Nn; n += stride) {
    float x[Dd];
#pragma unroll
    for (int d = 0; d < Dd; ++d) x[d] = Xd[n * Dd + d];
    float y = Yd[n];
    float h[HP1];
#pragma unroll
    for (int hh = 0; hh < Hh; ++hh) {
      float z = sb[hh];
#pragma unroll
      for (int d = 0; d < Dd; ++d) z += x[d] * sW[d * Hh + hh];
      h[hh] = 1.f / (1.f + __expf(-z));
    }
    h[40] = 1.f;
#pragma unroll
    for (int t = 0; t < Tt; ++t) {
      float pred = 0.f;
#pragma unroll
      for (int i = 0; i < HP1; ++i) pred += h[i] * sWM[t][i];
      float e = y - pred;
      acc[t] += e * e * Phi[n * Tt + t];
    }
  }
  for (int t = 0; t < Tt; ++t) {
    red[tid] = acc[t]; __syncthreads();
    for (int s = 128; s > 0; s >>= 1) {
      if (tid < s) red[tid] += red[tid + s];
      __syncthreads();
    }
    if (tid == 0) atomicAdd(&out[OFF_EB + t], 0.5f * red[0]);
    __syncthreads();
  }
}

extern "C" void kernel_launch(void* const* d_in, const int* in_sizes, int n_in,
                              void* d_out, int out_size, void* d_ws, size_t ws_size,
                              hipStream_t stream) {
  const float* Phi = (const float*)d_in[1];
  const float* Xd  = (const float*)d_in[2];
  const float* Yd  = (const float*)d_in[3];
  const float* W   = (const float*)d_in[4];
  const float* bb  = (const float*)d_in[5];
  const float* eA  = (const float*)d_in[6];
  const float* eB  = (const float*)d_in[7];
  const float* zA  = (const float*)d_in[8];
  const float* zB  = (const float*)d_in[9];
  float* out = (float*)d_out;
  float* ws  = (float*)d_ws;

  int nacc = NPADDED * Tt;  // 20480 floats
  hipLaunchKernelGGL(zero_ws_kernel, dim3((nacc + 511) / 512), dim3(512), 0, stream, ws, nacc);
  hipLaunchKernelGGL(gram_reduce, dim3(GRID1), dim3(256), 0, stream, Phi, Xd, Yd, W, bb, ws);
  hipLaunchKernelGGL(finalize_kernel, dim3(Tt), dim3(256), 0, stream, ws, eA, eB, zA, zB, out);
  hipLaunchKernelGGL(resid_kernel, dim3(256), dim3(256), 0, stream, Phi, Xd, Yd, W, bb, out);
}